// Round 1
// baseline (110.883 us; speedup 1.0000x reference)
//
#include <hip/hip_runtime.h>

#define BATCH 262144
#define NSITES 64
#define KPAD 40

typedef __attribute__((ext_vector_type(8))) short short8;
typedef __attribute__((ext_vector_type(4))) float f32x4;

__device__ __forceinline__ unsigned cvt_pk_bf16(float lo, float hi) {
  unsigned r;
  asm("v_cvt_pk_bf16_f32 %0, %1, %2" : "=v"(r) : "v"(lo), "v"(hi));
  return r;
}

// slot->logical chi permutation q and its inverse.
// k = [k4 k3 | k2 k1 k0] (g=k>>3, t=k&7) -> chi = 16*k2 + 4*(k4k3) + (k1k0)
__device__ __forceinline__ int qinv(int chi) {
  return (((chi >> 2) & 3) << 3) | (((chi >> 4) & 1) << 2) | (chi & 3);
}

struct Smem {
  alignas(16) short A[2][2][32][KPAD];  // [buf][m][row c][k] = E_m^T[c, q(k)] in bf16
  alignas(16) float c0p[2][32];         // c0p[m][k] = core0[m][q(k)]
  alignas(16) float cNp[32][2];         // cNp[k][l] = coreN[q(k)][l]
};

__device__ __forceinline__ void stage_load(const float* __restrict__ cores, int s, int tid,
                                           float sv[2][4]) {
#pragma unroll
  for (int r = 0; r < 2; ++r) {
    int V = tid + 256 * r;
    int c = V & 31, m = (V >> 5) & 1, b0 = (V >> 6) * 4;
    const float* p = cores + (s - 1) * 2048 + b0 * 64 + m * 32 + c;
    sv[r][0] = p[0];
    sv[r][1] = p[64];
    sv[r][2] = p[128];
    sv[r][3] = p[192];
  }
}

__device__ __forceinline__ void stage_write(short (*Ab)[32][KPAD], int tid,
                                            const float sv[2][4]) {
#pragma unroll
  for (int r = 0; r < 2; ++r) {
    int V = tid + 256 * r;
    int c = V & 31, m = (V >> 5) & 1, b0 = (V >> 6) * 4;
    float f0 = sv[r][0] - ((c == b0 + 0) ? 1.0f : 0.0f);
    float f1 = sv[r][1] - ((c == b0 + 1) ? 1.0f : 0.0f);
    float f2 = sv[r][2] - ((c == b0 + 2) ? 1.0f : 0.0f);
    float f3 = sv[r][3] - ((c == b0 + 3) ? 1.0f : 0.0f);
    unsigned p0 = cvt_pk_bf16(f0, f1);
    unsigned p1 = cvt_pk_bf16(f2, f3);
    int kq = (((b0 >> 2) & 3) << 3) | (((b0 >> 4) & 1) << 2);
    unsigned* dst = (unsigned*)&Ab[m][c][kq];
    dst[0] = p0;
    dst[1] = p1;
  }
}

__global__ __launch_bounds__(256, 4) void mps_chain_kernel(
    const float* __restrict__ X, const float* __restrict__ core0,
    const float* __restrict__ cores, const float* __restrict__ coreN,
    float* __restrict__ out) {
  __shared__ Smem sm;
  const int tid = threadIdx.x;
  const int lane = tid & 63;
  const int wave = tid >> 6;
  const int col = lane & 15;  // batch column within 16-wide tile
  const int g = lane >> 4;    // k-group
  const int abase = blockIdx.x * 256 + wave * 64;

  // ---- prologue: stage step-1 E matrices + permuted core0/coreN ----
  float sv[2][4];
  stage_load(cores, 1, tid, sv);
  if (tid < 64) {
    int m = tid >> 5, chi = tid & 31;
    sm.c0p[m][qinv(chi)] = core0[tid];
  } else if (tid < 128) {
    int t = tid - 64;
    int chi = t >> 1, cc = t & 1;
    sm.cNp[qinv(chi)][cc] = coreN[t];
  }
  stage_write(sm.A[0], tid, sv);
  __syncthreads();

  // ---- v0 = X[0] @ core0, in permuted slot order ----
  float v[4][8];
  const f32x4 c00 = *(const f32x4*)&sm.c0p[0][8 * g];
  const f32x4 c01 = *(const f32x4*)&sm.c0p[0][8 * g + 4];
  const f32x4 c10 = *(const f32x4*)&sm.c0p[1][8 * g];
  const f32x4 c11 = *(const f32x4*)&sm.c0p[1][8 * g + 4];
#pragma unroll
  for (int j = 0; j < 4; ++j) {
    const float2 xj = *(const float2*)(X + 2 * (size_t)(abase + j * 16 + col));
#pragma unroll
    for (int t = 0; t < 4; ++t) {
      v[j][t] = xj.x * c00[t] + xj.y * c10[t];
      v[j][4 + t] = xj.x * c01[t] + xj.y * c11[t];
    }
  }

  // ---- main chain: v <- (x0+x1)*v + x0*(v@E0) + x1*(v@E1) ----
  for (int s = 1; s < NSITES; ++s) {
    const int buf = (s - 1) & 1;
    if (s < NSITES - 1) stage_load(cores, s + 1, tid, sv);

    float2 x[4];
#pragma unroll
    for (int j = 0; j < 4; ++j)
      x[j] = *(const float2*)(X + 2 * ((size_t)s * BATCH + abase + j * 16 + col));

    const short8 A00 = *(const short8*)&sm.A[buf][0][col][8 * g];
    const short8 A01 = *(const short8*)&sm.A[buf][0][16 + col][8 * g];
    const short8 A10 = *(const short8*)&sm.A[buf][1][col][8 * g];
    const short8 A11 = *(const short8*)&sm.A[buf][1][16 + col][8 * g];

#pragma unroll
    for (int j = 0; j < 4; ++j) {
      union {
        short8 s8;
        unsigned u[4];
      } vb;
      vb.u[0] = cvt_pk_bf16(v[j][0], v[j][1]);
      vb.u[1] = cvt_pk_bf16(v[j][2], v[j][3]);
      vb.u[2] = cvt_pk_bf16(v[j][4], v[j][5]);
      vb.u[3] = cvt_pk_bf16(v[j][6], v[j][7]);
      const f32x4 z = {0.f, 0.f, 0.f, 0.f};
      f32x4 r0lo = __builtin_amdgcn_mfma_f32_16x16x32_bf16(A00, vb.s8, z, 0, 0, 0);
      f32x4 r0hi = __builtin_amdgcn_mfma_f32_16x16x32_bf16(A01, vb.s8, z, 0, 0, 0);
      f32x4 r1lo = __builtin_amdgcn_mfma_f32_16x16x32_bf16(A10, vb.s8, z, 0, 0, 0);
      f32x4 r1hi = __builtin_amdgcn_mfma_f32_16x16x32_bf16(A11, vb.s8, z, 0, 0, 0);
      const float s01 = x[j].x + x[j].y;
#pragma unroll
      for (int t = 0; t < 4; ++t) {
        v[j][t] = s01 * v[j][t] + x[j].x * r0lo[t] + x[j].y * r1lo[t];
        v[j][4 + t] = s01 * v[j][4 + t] + x[j].x * r0hi[t] + x[j].y * r1hi[t];
      }
    }

    if (s < NSITES - 1) stage_write(sm.A[buf ^ 1], tid, sv);
    __syncthreads();
  }

  // ---- epilogue: out = |v @ coreN| ----
#pragma unroll
  for (int j = 0; j < 4; ++j) {
    float p0 = 0.f, p1 = 0.f;
#pragma unroll
    for (int u = 0; u < 4; ++u) {
      const f32x4 cn = *(const f32x4*)&sm.cNp[8 * g + 2 * u][0];
      p0 += v[j][2 * u] * cn[0] + v[j][2 * u + 1] * cn[2];
      p1 += v[j][2 * u] * cn[1] + v[j][2 * u + 1] * cn[3];
    }
    p0 += __shfl_xor(p0, 16);
    p0 += __shfl_xor(p0, 32);
    p1 += __shfl_xor(p1, 16);
    p1 += __shfl_xor(p1, 32);
    if (g == 0) {
      const int a = abase + j * 16 + col;
      out[2 * a] = fabsf(p0);
      out[2 * a + 1] = fabsf(p1);
    }
  }
}

extern "C" void kernel_launch(void* const* d_in, const int* in_sizes, int n_in,
                              void* d_out, int out_size, void* d_ws, size_t ws_size,
                              hipStream_t stream) {
  const float* X = (const float*)d_in[0];
  const float* core0 = (const float*)d_in[1];
  const float* cores = (const float*)d_in[2];
  const float* coreN = (const float*)d_in[3];
  float* out = (float*)d_out;
  dim3 grid(BATCH / 256);
  dim3 block(256);
  hipLaunchKernelGGL(mps_chain_kernel, grid, block, 0, stream, X, core0, cores, coreN, out);
}